// Round 1
// baseline (46.711 us; speedup 1.0000x reference)
//
#include <hip/hip_runtime.h>

typedef __bf16 bf16x8 __attribute__((ext_vector_type(8)));
typedef float f32x16 __attribute__((ext_vector_type(16)));
typedef float f32x4  __attribute__((ext_vector_type(4)));
typedef unsigned int u32x4 __attribute__((ext_vector_type(4)));

#define HEAD_DIM 128
#define D_MODEL  4096   // 32 heads * 128

// pack two floats into one u32 of 2x bf16 (RNE via __bf16 cast)
__device__ __forceinline__ unsigned pack_bf16(float lo, float hi) {
    unsigned a = (unsigned)__builtin_bit_cast(unsigned short, (__bf16)lo);
    unsigned b = (unsigned)__builtin_bit_cast(unsigned short, (__bf16)hi);
    return a | (b << 16);
}

// One wave per batch row b. Per-b attention: Q,K,V are 32x128.
//   scores^T = mfma(A=K, B=Q)  -> D[kv][h]: lane holds h = lane&31,
//   kv(reg) = (reg&3) + 8*(reg>>2) + 4*(lane>>5)   (verified 32x32 C/D layout)
// softmax over kv is 15 in-lane fmax + one shfl_xor(32); then probs are
// repacked into the A-fragment layout for PV via bf16 packing + lane^32
// exchange; PV = mfma(A=P^T, B=V) over 4 d-chunks x 2 k-steps.
__global__ __launch_bounds__(256, 4) void attn_kernel(
    const float* __restrict__ q,
    const float* __restrict__ k,
    const float* __restrict__ v,
    float* __restrict__ out)
{
    constexpr float SCALE_LOG2E = 0.08838834764831845f * 1.4426950408889634f;

    const int lane = threadIdx.x & 63;
    const int b    = blockIdx.x * 4 + (threadIdx.x >> 6);
    const int r    = lane & 31;
    const int hi   = lane >> 5;

    const float* qb = q + (size_t)b * D_MODEL;
    const float* kb = k + (size_t)b * D_MODEL;
    const float* vb = v + (size_t)b * D_MODEL;

    // ---------- scores^T = K * Q^T : D[kv][h] ----------
    f32x16 acc = {};
    const int rowoff = r * HEAD_DIM + hi * 8;
#pragma unroll
    for (int s = 0; s < 8; ++s) {
        const float* qp = qb + rowoff + s * 16;
        const float* kp = kb + rowoff + s * 16;
        f32x4 q0 = *(const f32x4*)(qp);
        f32x4 q1 = *(const f32x4*)(qp + 4);
        f32x4 k0 = *(const f32x4*)(kp);
        f32x4 k1 = *(const f32x4*)(kp + 4);
        bf16x8 aK, bQ;
#pragma unroll
        for (int j = 0; j < 4; ++j) { aK[j] = (__bf16)k0[j]; aK[4 + j] = (__bf16)k1[j]; }
#pragma unroll
        for (int j = 0; j < 4; ++j) { bQ[j] = (__bf16)q0[j]; bQ[4 + j] = (__bf16)q1[j]; }
        acc = __builtin_amdgcn_mfma_f32_32x32x16_bf16(aK, bQ, acc, 0, 0, 0);
    }

    // ---------- softmax over kv (h = r is lane-local) ----------
    float m = acc[0];
#pragma unroll
    for (int i = 1; i < 16; ++i) m = fmaxf(m, acc[i]);
    m = fmaxf(m, __shfl_xor(m, 32, 64));

    float p[16];
    float sum = 0.f;
#pragma unroll
    for (int i = 0; i < 16; ++i) {
        p[i] = __builtin_amdgcn_exp2f((acc[i] - m) * SCALE_LOG2E);
        sum += p[i];
    }
    sum += __shfl_xor(sum, 32, 64);
    const float inv = __builtin_amdgcn_rcpf(sum);
#pragma unroll
    for (int i = 0; i < 16; ++i) p[i] *= inv;

    // ---------- repack into A-fragment of P^T[h][kv] ----------
    // word i = pack(p[2i], p[2i+1]); A-frag step t needs
    //   lo lanes: [W0self, W1self, W0partner, W1partner]
    //   hi lanes: [W2partner, W3partner, W2self, W3self]
    unsigned w[8];
#pragma unroll
    for (int i = 0; i < 8; ++i) w[i] = pack_bf16(p[2 * i], p[2 * i + 1]);

    bf16x8 pa[2];
#pragma unroll
    for (int t = 0; t < 2; ++t) {
        unsigned W0 = w[4 * t], W1 = w[4 * t + 1], W2 = w[4 * t + 2], W3 = w[4 * t + 3];
        unsigned X0 = (unsigned)__shfl_xor((int)W0, 32, 64);
        unsigned X1 = (unsigned)__shfl_xor((int)W1, 32, 64);
        unsigned X2 = (unsigned)__shfl_xor((int)W2, 32, 64);
        unsigned X3 = (unsigned)__shfl_xor((int)W3, 32, 64);
        u32x4 wv;
        wv[0] = hi ? X2 : W0;
        wv[1] = hi ? X3 : W1;
        wv[2] = hi ? W2 : X0;
        wv[3] = hi ? W3 : X1;
        pa[t] = __builtin_bit_cast(bf16x8, wv);
    }

    // ---------- out[h][d] = P^T * V ----------
    float* ob = out + (size_t)b * D_MODEL;
#pragma unroll
    for (int c = 0; c < 4; ++c) {
        f32x16 oacc = {};
#pragma unroll
        for (int t = 0; t < 2; ++t) {
            const float* vp = vb + (t * 16 + hi * 8) * HEAD_DIM + c * 32 + r;
            bf16x8 bV;
#pragma unroll
            for (int j = 0; j < 8; ++j) bV[j] = (__bf16)vp[(size_t)j * HEAD_DIM];
            oacc = __builtin_amdgcn_mfma_f32_32x32x16_bf16(pa[t], bV, oacc, 0, 0, 0);
        }
        float* op = ob + c * 32 + r;
#pragma unroll
        for (int reg = 0; reg < 16; ++reg) {
            const int h = (reg & 3) + 8 * (reg >> 2) + 4 * hi;
            op[(size_t)h * HEAD_DIM] = oacc[reg];
        }
    }
}

extern "C" void kernel_launch(void* const* d_in, const int* in_sizes, int n_in,
                              void* d_out, int out_size, void* d_ws, size_t ws_size,
                              hipStream_t stream) {
    const float* q = (const float*)d_in[0];
    const float* k = (const float*)d_in[1];
    const float* v = (const float*)d_in[2];
    float* out = (float*)d_out;
    const int B = in_sizes[0] / D_MODEL;   // 4096
    attn_kernel<<<dim3(B / 4), dim3(256), 0, stream>>>(q, k, v, out);
}